// Round 1
// baseline (2081.190 us; speedup 1.0000x reference)
//
#include <hip/hip_runtime.h>
#include <math.h>

#define NB 2
#define NC 50
#define NCR 25
#define H0 48
#define W0 48
#define HW0 2304
#define LTOT 7470
#define K225 225
#define CD 450   // C*9

__device__ __forceinline__ void decode_pix(int pix, int& s, int& off, int& d) {
  if (pix < 2304)      { s = 0; off = 0;    d = 48; }
  else if (pix < 4153) { s = 1; off = 2304; d = 43; }
  else if (pix < 5597) { s = 2; off = 4153; d = 38; }
  else if (pix < 6686) { s = 3; off = 5597; d = 33; }
  else                 { s = 4; off = 6686; d = 28; }
}

__device__ __forceinline__ float cubw(float t) {
  const float a = -0.75f;
  float at = fabsf(t);
  float w1 = ((a + 2.f) * at - (a + 3.f)) * at * at + 1.f;
  float w2 = (((at - 5.f) * at + 8.f) * at - 4.f) * a;
  return at <= 1.f ? w1 : (at < 2.f ? w2 : 0.f);
}

// out[b,o,pix] = prelu(sum_c W[o,c]*in[b,c,pix] + bias[o])
__global__ void k_conv1x1(const float* __restrict__ in, const float* __restrict__ Wt,
                          const float* __restrict__ bias, const float* __restrict__ slope,
                          float* __restrict__ out, int Cin, int O, int P) {
  int t = blockIdx.x * blockDim.x + threadIdx.x;
  int total = NB * O * P;
  if (t >= total) return;
  int pix = t % P;
  int o = (t / P) % O;
  int b = t / (P * O);
  float acc = bias[o];
  const float* ip = in + (size_t)b * Cin * P + pix;
  const float* wr = Wt + o * Cin;
  for (int c = 0; c < Cin; ++c) acc = fmaf(wr[c], ip[(size_t)c * P], acc);
  float a = slope[0];
  out[t] = acc >= 0.f ? acc : a * acc;
}

// refs[b,c,pix] over concatenated scale grids; s=0 copy of x, else bicubic align_corners
__global__ void k_build_refs(const float* __restrict__ x, float* __restrict__ refs) {
  int t = blockIdx.x * blockDim.x + threadIdx.x;
  int total = NB * NC * LTOT;
  if (t >= total) return;
  int pix = t % LTOT;
  int c = (t / LTOT) % NC;
  int b = t / (LTOT * NC);
  int s, off, d;
  decode_pix(pix, s, off, d);
  float v;
  const float* xb = x + ((size_t)b * NC + c) * HW0;
  if (s == 0) {
    v = xb[pix];
  } else {
    int rem = pix - off;
    int oy = rem / d, ox = rem % d;
    float scale = 47.f / (float)(d - 1);
    float sy = oy * scale, sx = ox * scale;
    float fy0 = floorf(sy), fx0 = floorf(sx);
    int iy = (int)fy0, ix = (int)fx0;
    float fy = sy - fy0, fx = sx - fx0;
    float wy[4], wx[4];
#pragma unroll
    for (int dd = 0; dd < 4; ++dd) {
      wy[dd] = cubw(fy - (float)(dd - 1));
      wx[dd] = cubw(fx - (float)(dd - 1));
    }
    float acc = 0.f;
#pragma unroll
    for (int p = 0; p < 4; ++p) {
      int yy = min(max(iy + p - 1, 0), 47);
      float rowacc = 0.f;
#pragma unroll
      for (int q = 0; q < 4; ++q) {
        int xx = min(max(ix + q - 1, 0), 47);
        rowacc = fmaf(wx[q], xb[yy * 48 + xx], rowacc);
      }
      acc = fmaf(wy[p], rowacc, acc);
    }
    v = acc;
  }
  refs[t] = v;
}

// xq[b,p,k]: 3x3 zero-padded patches of match_base
__global__ void k_build_xq(const float* __restrict__ mb, float* __restrict__ xq) {
  int bp = blockIdx.x;
  int b = bp / HW0, p = bp % HW0;
  int i = p / W0, j = p % W0;
  int k = threadIdx.x;
  if (k >= K225) return;
  int c = k / 9, r = k % 9, di = r / 3, dj = r % 3;
  int yy = i + di - 1, xx = j + dj - 1;
  float v = (yy >= 0 && yy < H0 && xx >= 0 && xx < W0)
                ? mb[((size_t)b * NCR + c) * HW0 + yy * W0 + xx] : 0.f;
  xq[(size_t)bp * K225 + k] = v;
}

// wn[b,l,k] = patch(m)/max(||patch||,1e-4) * 10  (softmax scale folded)
__global__ void k_build_wn(const float* __restrict__ m, float* __restrict__ wn) {
  __shared__ float red[256];
  int bl = blockIdx.x;
  int b = bl / LTOT, l = bl % LTOT;
  int s, off, d;
  decode_pix(l, s, off, d);
  int rem = l - off;
  int y = rem / d, x = rem % d;
  int k = threadIdx.x;
  float v = 0.f;
  if (k < K225) {
    int c = k / 9, r = k % 9, di = r / 3, dj = r % 3;
    int yy = y + di - 1, xx = x + dj - 1;
    if (yy >= 0 && yy < d && xx >= 0 && xx < d)
      v = m[((size_t)b * NCR + c) * LTOT + off + yy * d + xx];
  }
  red[k] = v * v;
  __syncthreads();
  for (int st = 128; st > 0; st >>= 1) {
    if (k < st) red[k] += red[k + st];
    __syncthreads();
  }
  float norm = sqrtf(red[0]);
  float sc = 10.f / fmaxf(norm, 1e-4f);
  if (k < K225) wn[(size_t)bl * K225 + k] = v * sc;
}

// Braw[b,l,c*9+kh*3+kw] = 0.25 * zero-padded patch of base (values); /4 folded
__global__ void k_build_braw(const float* __restrict__ base, float* __restrict__ Braw) {
  int t = blockIdx.x * blockDim.x + threadIdx.x;
  int total = NB * LTOT * CD;
  if (t >= total) return;
  int cd = t % CD;
  int l = (t / CD) % LTOT;
  int b = t / (CD * LTOT);
  int s, off, d;
  decode_pix(l, s, off, d);
  int rem = l - off;
  int y = rem / d, x = rem % d;
  int c = cd / 9, r = cd % 9, di = r / 3, dj = r % 3;
  int yy = y + di - 1, xx = x + dj - 1;
  float v = (yy >= 0 && yy < d && xx >= 0 && xx < d)
                ? base[((size_t)b * NC + c) * LTOT + off + yy * d + xx] : 0.f;
  Braw[t] = 0.25f * v;
}

// C[m,n] = sum_k A[m,k]*B[n,k]  (NT, both K-contiguous)
__global__ __launch_bounds__(256) void k_gemm_nt(
    const float* __restrict__ A, const float* __restrict__ Bm, float* __restrict__ Cm,
    int M, int N, int K, int lda, int ldb, int ldc,
    long long sA, long long sB, long long sC) {
  __shared__ float As[64][17];
  __shared__ float Bs[64][17];
  const float* Ab = A + blockIdx.z * sA;
  const float* Bb = Bm + blockIdx.z * sB;
  float* Cb = Cm + blockIdx.z * sC;
  int m0 = blockIdx.y * 64, n0 = blockIdx.x * 64;
  int tid = threadIdx.x;
  int tx = tid & 15, ty = tid >> 4;
  float acc[4][4] = {{0.f}};
  for (int k0 = 0; k0 < K; k0 += 16) {
#pragma unroll
    for (int i = 0; i < 4; ++i) {
      int idx = tid + i * 256;
      int r = idx >> 4, kk = idx & 15;
      int k = k0 + kk;
      int mm = m0 + r;
      As[r][kk] = (mm < M && k < K) ? Ab[(size_t)mm * lda + k] : 0.f;
      int nn = n0 + r;
      Bs[r][kk] = (nn < N && k < K) ? Bb[(size_t)nn * ldb + k] : 0.f;
    }
    __syncthreads();
#pragma unroll
    for (int kk = 0; kk < 16; ++kk) {
      float av[4], bv[4];
#pragma unroll
      for (int i = 0; i < 4; ++i) av[i] = As[ty * 4 + i][kk];
#pragma unroll
      for (int j = 0; j < 4; ++j) bv[j] = Bs[tx * 4 + j][kk];
#pragma unroll
      for (int i = 0; i < 4; ++i)
#pragma unroll
        for (int j = 0; j < 4; ++j) acc[i][j] = fmaf(av[i], bv[j], acc[i][j]);
    }
    __syncthreads();
  }
#pragma unroll
  for (int i = 0; i < 4; ++i) {
    int mm = m0 + ty * 4 + i;
    if (mm >= M) continue;
#pragma unroll
    for (int j = 0; j < 4; ++j) {
      int nn = n0 + tx * 4 + j;
      if (nn < N) Cb[(size_t)mm * ldc + nn] = acc[i][j];
    }
  }
}

// C[m,n] = sum_k A[m,k]*B[k,n]  (NN)
__global__ __launch_bounds__(256) void k_gemm_nn(
    const float* __restrict__ A, const float* __restrict__ Bm, float* __restrict__ Cm,
    int M, int N, int K, int lda, int ldb, int ldc,
    long long sA, long long sB, long long sC) {
  __shared__ float As[64][17];
  __shared__ float Bs[16][64];
  const float* Ab = A + blockIdx.z * sA;
  const float* Bb = Bm + blockIdx.z * sB;
  float* Cb = Cm + blockIdx.z * sC;
  int m0 = blockIdx.y * 64, n0 = blockIdx.x * 64;
  int tid = threadIdx.x;
  int tx = tid & 15, ty = tid >> 4;
  float acc[4][4] = {{0.f}};
  for (int k0 = 0; k0 < K; k0 += 16) {
#pragma unroll
    for (int i = 0; i < 4; ++i) {
      int idx = tid + i * 256;
      int r = idx >> 4, kk = idx & 15;
      int k = k0 + kk;
      int mm = m0 + r;
      As[r][kk] = (mm < M && k < K) ? Ab[(size_t)mm * lda + k] : 0.f;
    }
#pragma unroll
    for (int i = 0; i < 4; ++i) {
      int idx = tid + i * 256;
      int kk = idx >> 6, cc = idx & 63;
      int k = k0 + kk;
      int nn = n0 + cc;
      Bs[kk][cc] = (k < K && nn < N) ? Bb[(size_t)k * ldb + nn] : 0.f;
    }
    __syncthreads();
#pragma unroll
    for (int kk = 0; kk < 16; ++kk) {
      float av[4], bv[4];
#pragma unroll
      for (int i = 0; i < 4; ++i) av[i] = As[ty * 4 + i][kk];
#pragma unroll
      for (int j = 0; j < 4; ++j) bv[j] = Bs[kk][tx * 4 + j];
#pragma unroll
      for (int i = 0; i < 4; ++i)
#pragma unroll
        for (int j = 0; j < 4; ++j) acc[i][j] = fmaf(av[i], bv[j], acc[i][j]);
    }
    __syncthreads();
  }
#pragma unroll
  for (int i = 0; i < 4; ++i) {
    int mm = m0 + ty * 4 + i;
    if (mm >= M) continue;
#pragma unroll
    for (int j = 0; j < 4; ++j) {
      int nn = n0 + tx * 4 + j;
      if (nn < N) Cb[(size_t)mm * ldc + nn] = acc[i][j];
    }
  }
}

// in-place softmax over contiguous rows of length LTOT
__global__ void k_softmax(float* __restrict__ S) {
  __shared__ float buf[LTOT];
  __shared__ float red[256];
  size_t row = blockIdx.x;
  float* r = S + row * LTOT;
  int tid = threadIdx.x;
  float mx = -1e30f;
  for (int i = tid; i < LTOT; i += 256) {
    float v = r[i];
    buf[i] = v;
    mx = fmaxf(mx, v);
  }
  red[tid] = mx;
  __syncthreads();
  for (int st = 128; st > 0; st >>= 1) {
    if (tid < st) red[tid] = fmaxf(red[tid], red[tid + st]);
    __syncthreads();
  }
  mx = red[0];
  __syncthreads();
  float sm = 0.f;
  for (int i = tid; i < LTOT; i += 256) {
    float e = expf(buf[i] - mx);
    buf[i] = e;
    sm += e;
  }
  red[tid] = sm;
  __syncthreads();
  for (int st = 128; st > 0; st >>= 1) {
    if (tid < st) red[tid] += red[tid + st];
    __syncthreads();
  }
  float inv = 1.f / red[0];
  for (int i = tid; i < LTOT; i += 256) r[i] = buf[i] * inv;
}

// out[b,c,i,j] = sum_{kh,kw} G[b, (i-kh+1, j-kw+1), c*9+kh*3+kw] + x[b,c,i,j]
__global__ void k_final(const float* __restrict__ G, const float* __restrict__ x,
                        float* __restrict__ out) {
  int t = blockIdx.x * blockDim.x + threadIdx.x;
  int total = NB * NC * HW0;
  if (t >= total) return;
  int p = t % HW0;
  int c = (t / HW0) % NC;
  int b = t / (HW0 * NC);
  int i = p / W0, j = p % W0;
  float sum = 0.f;
#pragma unroll
  for (int kh = 0; kh < 3; ++kh) {
    int pi = i - kh + 1;
    if (pi < 0 || pi >= H0) continue;
#pragma unroll
    for (int kw = 0; kw < 3; ++kw) {
      int pj = j - kw + 1;
      if (pj < 0 || pj >= W0) continue;
      sum += G[((size_t)b * HW0 + pi * W0 + pj) * CD + c * 9 + kh * 3 + kw];
    }
  }
  out[t] = sum + x[t];
}

extern "C" void kernel_launch(void* const* d_in, const int* in_sizes, int n_in,
                              void* d_out, int out_size, void* d_ws, size_t ws_size,
                              hipStream_t stream) {
  const float* x   = (const float*)d_in[0];
  const float* Wmb = (const float*)d_in[1];
  const float* bmb = (const float*)d_in[2];
  const float* amb = (const float*)d_in[3];
  const float* Wm  = (const float*)d_in[4];
  const float* bm  = (const float*)d_in[5];
  const float* am  = (const float*)d_in[6];
  const float* Wa  = (const float*)d_in[7];
  const float* ba  = (const float*)d_in[8];
  const float* aa  = (const float*)d_in[9];
  float* out = (float*)d_out;
  float* ws = (float*)d_ws;

  size_t off = 0;
  float* mb   = ws + off; off += (size_t)NB * NCR * HW0;   // 115200
  float* refs = ws + off; off += (size_t)NB * NC * LTOT;   // 747000
  float* base = ws + off; off += (size_t)NB * NC * LTOT;   // 747000
  float* m    = ws + off; off += (size_t)NB * NCR * LTOT;  // 373500
  float* wn   = ws + off; off += (size_t)NB * LTOT * K225; // 3361500
  float* xq   = ws + off; off += (size_t)NB * HW0 * K225;  // 1036800
  float* Braw = ws + off; off += (size_t)NB * LTOT * CD;   // 6723000
  float* G    = ws + off; off += (size_t)NB * HW0 * CD;    // 2073600
  float* scbuf = ws + off;

  size_t ws_floats = ws_size / 4;
  size_t avail = (ws_floats > off) ? (ws_floats - off) : 0;
  int pc = HW0;  // p-chunk for the scores buffer [NB][pc][LTOT]
  while (pc > 36 && (size_t)NB * pc * LTOT > avail) pc >>= 1;

  const int th = 256;
  k_conv1x1<<<(NB * NCR * HW0 + th - 1) / th, th, 0, stream>>>(x, Wmb, bmb, amb, mb, NC, NCR, HW0);
  k_build_refs<<<(NB * NC * LTOT + th - 1) / th, th, 0, stream>>>(x, refs);
  k_conv1x1<<<(NB * NC * LTOT + th - 1) / th, th, 0, stream>>>(refs, Wa, ba, aa, base, NC, NC, LTOT);
  k_conv1x1<<<(NB * NCR * LTOT + th - 1) / th, th, 0, stream>>>(refs, Wm, bm, am, m, NC, NCR, LTOT);
  k_build_xq<<<NB * HW0, 256, 0, stream>>>(mb, xq);
  k_build_wn<<<NB * LTOT, 256, 0, stream>>>(m, wn);
  k_build_braw<<<(NB * LTOT * CD + th - 1) / th, th, 0, stream>>>(base, Braw);

  for (int p0 = 0; p0 < HW0; p0 += pc) {
    dim3 g1((LTOT + 63) / 64, (pc + 63) / 64, NB);
    k_gemm_nt<<<g1, 256, 0, stream>>>(xq + (size_t)p0 * K225, wn, scbuf,
                                      pc, LTOT, K225, K225, K225, LTOT,
                                      (long long)HW0 * K225, (long long)LTOT * K225,
                                      (long long)pc * LTOT);
    k_softmax<<<NB * pc, 256, 0, stream>>>(scbuf);
    dim3 g2((CD + 63) / 64, (pc + 63) / 64, NB);
    k_gemm_nn<<<g2, 256, 0, stream>>>(scbuf, Braw, G + (size_t)p0 * CD,
                                      pc, CD, LTOT, LTOT, CD, CD,
                                      (long long)pc * LTOT, (long long)LTOT * CD,
                                      (long long)HW0 * CD);
  }
  k_final<<<(NB * NC * HW0 + th - 1) / th, th, 0, stream>>>(G, x, out);
}

// Round 2
// 453.582 us; speedup vs baseline: 4.5883x; 4.5883x over previous
//
#include <hip/hip_runtime.h>
#include <math.h>

#define NB 2
#define NC 50
#define NCR 25
#define H0 48
#define W0 48
#define HW0 2304
#define LTOT 7470
#define LP 7552      // LTOT padded to 128
#define K225 225
#define KP 256       // 225 padded to 256
#define CD 450       // C*9
#define CDP 512      // padded to 128

typedef _Float16 f16x8 __attribute__((ext_vector_type(8)));
typedef float f32x4 __attribute__((ext_vector_type(4)));

#define GLOAD_LDS16(gp, lp) __builtin_amdgcn_global_load_lds( \
    (const __attribute__((address_space(1))) void*)(gp),      \
    (__attribute__((address_space(3))) void*)(lp), 16, 0, 0)

__device__ __forceinline__ void decode_pix(int pix, int& s, int& off, int& d) {
  if (pix < 2304)      { s = 0; off = 0;    d = 48; }
  else if (pix < 4153) { s = 1; off = 2304; d = 43; }
  else if (pix < 5597) { s = 2; off = 4153; d = 38; }
  else if (pix < 6686) { s = 3; off = 5597; d = 33; }
  else                 { s = 4; off = 6686; d = 28; }
}

__device__ __forceinline__ float cubw(float t) {
  const float a = -0.75f;
  float at = fabsf(t);
  float w1 = ((a + 2.f) * at - (a + 3.f)) * at * at + 1.f;
  float w2 = (((at - 5.f) * at + 8.f) * at - 4.f) * a;
  return at <= 1.f ? w1 : (at < 2.f ? w2 : 0.f);
}

// out[b,o,pix] = prelu(sum_c W[o,c]*in[b,c,pix] + bias[o])
__global__ void k_conv1x1(const float* __restrict__ in, const float* __restrict__ Wt,
                          const float* __restrict__ bias, const float* __restrict__ slope,
                          float* __restrict__ out, int Cin, int O, int P) {
  int t = blockIdx.x * blockDim.x + threadIdx.x;
  int total = NB * O * P;
  if (t >= total) return;
  int pix = t % P;
  int o = (t / P) % O;
  int b = t / (P * O);
  float acc = bias[o];
  const float* ip = in + (size_t)b * Cin * P + pix;
  const float* wr = Wt + o * Cin;
  for (int c = 0; c < Cin; ++c) acc = fmaf(wr[c], ip[(size_t)c * P], acc);
  float a = slope[0];
  out[t] = acc >= 0.f ? acc : a * acc;
}

// refs[b,c,pix] over concatenated scale grids
__global__ void k_build_refs(const float* __restrict__ x, float* __restrict__ refs) {
  int t = blockIdx.x * blockDim.x + threadIdx.x;
  int total = NB * NC * LTOT;
  if (t >= total) return;
  int pix = t % LTOT;
  int c = (t / LTOT) % NC;
  int b = t / (LTOT * NC);
  int s, off, d;
  decode_pix(pix, s, off, d);
  float v;
  const float* xb = x + ((size_t)b * NC + c) * HW0;
  if (s == 0) {
    v = xb[pix];
  } else {
    int rem = pix - off;
    int oy = rem / d, ox = rem % d;
    float scale = 47.f / (float)(d - 1);
    float sy = oy * scale, sx = ox * scale;
    float fy0 = floorf(sy), fx0 = floorf(sx);
    int iy = (int)fy0, ix = (int)fx0;
    float fy = sy - fy0, fx = sx - fx0;
    float wy[4], wx[4];
#pragma unroll
    for (int dd = 0; dd < 4; ++dd) {
      wy[dd] = cubw(fy - (float)(dd - 1));
      wx[dd] = cubw(fx - (float)(dd - 1));
    }
    float acc = 0.f;
#pragma unroll
    for (int p = 0; p < 4; ++p) {
      int yy = min(max(iy + p - 1, 0), 47);
      float rowacc = 0.f;
#pragma unroll
      for (int q = 0; q < 4; ++q) {
        int xx = min(max(ix + q - 1, 0), 47);
        rowacc = fmaf(wx[q], xb[yy * 48 + xx], rowacc);
      }
      acc = fmaf(wy[p], rowacc, acc);
    }
    v = acc;
  }
  refs[t] = v;
}

// xq16[b,p,k] fp16, k in [0,256), zero pad k>=225
__global__ void k_build_xq(const float* __restrict__ mb, _Float16* __restrict__ xq) {
  int bp = blockIdx.x;
  int b = bp / HW0, p = bp % HW0;
  int i = p / W0, j = p % W0;
  int k = threadIdx.x;
  float v = 0.f;
  if (k < K225) {
    int c = k / 9, r = k % 9, di = r / 3, dj = r % 3;
    int yy = i + di - 1, xx = j + dj - 1;
    if (yy >= 0 && yy < H0 && xx >= 0 && xx < W0)
      v = mb[((size_t)b * NCR + c) * HW0 + yy * W0 + xx];
  }
  xq[(size_t)bp * KP + k] = (_Float16)v;
}

// wn16[b,l,k] = patch(m)/max(||patch||,1e-4) * 10, fp16; rows l>=LTOT all zero
__global__ void k_build_wn(const float* __restrict__ m, _Float16* __restrict__ wn) {
  __shared__ float red[256];
  int bl = blockIdx.x;
  int b = bl / LP, l = bl % LP;
  int k = threadIdx.x;
  if (l >= LTOT) {
    wn[(size_t)bl * KP + k] = (_Float16)0.f;
    return;
  }
  int s, off, d;
  decode_pix(l, s, off, d);
  int rem = l - off;
  int y = rem / d, x = rem % d;
  float v = 0.f;
  if (k < K225) {
    int c = k / 9, r = k % 9, di = r / 3, dj = r % 3;
    int yy = y + di - 1, xx = x + dj - 1;
    if (yy >= 0 && yy < d && xx >= 0 && xx < d)
      v = m[((size_t)b * NCR + c) * LTOT + off + yy * d + xx];
  }
  red[k] = v * v;
  __syncthreads();
  for (int st = 128; st > 0; st >>= 1) {
    if (k < st) red[k] += red[k + st];
    __syncthreads();
  }
  float norm = sqrtf(red[0]);
  float sc = 10.f / fmaxf(norm, 1e-4f);
  wn[(size_t)bl * KP + k] = (_Float16)(v * sc);
}

// BrawT[b, cd(512), l(LP)] fp16 = 0.25*patch(base); zero outside
__global__ void k_build_brawT(const float* __restrict__ base, _Float16* __restrict__ BT) {
  int t = blockIdx.x * blockDim.x + threadIdx.x;
  int total = NB * CDP * LP;
  if (t >= total) return;
  int l = t % LP;
  int cd = (t / LP) % CDP;
  int b = t / (LP * CDP);
  float v = 0.f;
  if (cd < CD && l < LTOT) {
    int s, off, d;
    decode_pix(l, s, off, d);
    int rem = l - off;
    int y = rem / d, x = rem % d;
    int c = cd / 9, r = cd % 9, di = r / 3, dj = r % 3;
    int yy = y + di - 1, xx = x + dj - 1;
    if (yy >= 0 && yy < d && xx >= 0 && xx < d)
      v = 0.25f * base[((size_t)b * NC + c) * LTOT + off + yy * d + xx];
  }
  BT[t] = (_Float16)v;
}

// C[m,n] = sum_k A[m,k]*B[n,k]; A [M,K] lda=K-major, B [N,K]. fp16 in, fp32 out.
// M,N multiples of 128 (buffers padded); K multiple of 32. Writes n < Nreal only.
__global__ __launch_bounds__(256) void k_gemm_nt_f16(
    const _Float16* __restrict__ A, const _Float16* __restrict__ Bm,
    float* __restrict__ Cm, int K, int lda, int ldb, int ldc, int Nreal,
    long long sA, long long sB, long long sC) {
  __shared__ _Float16 As[128 * 32];
  __shared__ _Float16 Bs[128 * 32];
  const _Float16* Ab = A + blockIdx.z * sA;
  const _Float16* Bb = Bm + blockIdx.z * sB;
  float* Cb = Cm + blockIdx.z * sC;
  int m0 = blockIdx.y * 128, n0 = blockIdx.x * 128;
  int t = threadIdx.x;
  int lane = t & 63, wid = t >> 6;
  int wr = wid >> 1, wc = wid & 1;
  f32x4 acc[4][4] = {};
  for (int k0 = 0; k0 < K; k0 += 32) {
#pragma unroll
    for (int i = 0; i < 2; ++i) {
      int e = i * 256 + t;
      int r = e >> 2, c = e & 3;
      GLOAD_LDS16(Ab + (size_t)(m0 + r) * lda + k0 + c * 8, As + (size_t)e * 8);
      GLOAD_LDS16(Bb + (size_t)(n0 + r) * ldb + k0 + c * 8, Bs + (size_t)e * 8);
    }
    __syncthreads();
    int rla = (wr * 64 + (lane & 15)) * 32 + (lane >> 4) * 8;
    int rlb = (wc * 64 + (lane & 15)) * 32 + (lane >> 4) * 8;
    f16x8 af[4], bf[4];
#pragma unroll
    for (int mi = 0; mi < 4; ++mi) af[mi] = *(const f16x8*)&As[rla + mi * 16 * 32];
#pragma unroll
    for (int ni = 0; ni < 4; ++ni) bf[ni] = *(const f16x8*)&Bs[rlb + ni * 16 * 32];
#pragma unroll
    for (int mi = 0; mi < 4; ++mi)
#pragma unroll
      for (int ni = 0; ni < 4; ++ni)
        acc[mi][ni] = __builtin_amdgcn_mfma_f32_16x16x32_f16(af[mi], bf[ni], acc[mi][ni], 0, 0, 0);
    __syncthreads();
  }
  int col0 = lane & 15;
  int row0 = (lane >> 4) * 4;
#pragma unroll
  for (int mi = 0; mi < 4; ++mi) {
#pragma unroll
    for (int ni = 0; ni < 4; ++ni) {
      int n = n0 + wc * 64 + ni * 16 + col0;
      if (n >= Nreal) continue;
#pragma unroll
      for (int r = 0; r < 4; ++r) {
        int mrow = m0 + wr * 64 + mi * 16 + row0 + r;
        Cb[(size_t)mrow * ldc + n] = acc[mi][ni][r];
      }
    }
  }
}

// softmax over l<LTOT of scores row [LP] fp32 -> attn row [LP] fp16 (pad zeroed)
__global__ void k_softmax(const float* __restrict__ S, _Float16* __restrict__ Aout) {
  __shared__ float buf[LTOT];
  __shared__ float red[256];
  size_t row = blockIdx.x;
  const float* r = S + row * LP;
  _Float16* w = Aout + row * LP;
  int tid = threadIdx.x;
  float mx = -1e30f;
  for (int i = tid; i < LTOT; i += 256) {
    float v = r[i];
    buf[i] = v;
    mx = fmaxf(mx, v);
  }
  red[tid] = mx;
  __syncthreads();
  for (int st = 128; st > 0; st >>= 1) {
    if (tid < st) red[tid] = fmaxf(red[tid], red[tid + st]);
    __syncthreads();
  }
  mx = red[0];
  __syncthreads();
  float sm = 0.f;
  for (int i = tid; i < LTOT; i += 256) {
    float e = __expf(buf[i] - mx);
    buf[i] = e;
    sm += e;
  }
  red[tid] = sm;
  __syncthreads();
  for (int st = 128; st > 0; st >>= 1) {
    if (tid < st) red[tid] += red[tid + st];
    __syncthreads();
  }
  float inv = 1.f / red[0];
  for (int i = tid; i < LTOT; i += 256) w[i] = (_Float16)(buf[i] * inv);
  for (int i = LTOT + tid; i < LP; i += 256) w[i] = (_Float16)0.f;
}

// out[b,c,i,j] = sum_{kh,kw} G[b,(i-kh+1,j-kw+1), c*9+kh*3+kw] + x
__global__ void k_final(const float* __restrict__ G, const float* __restrict__ x,
                        float* __restrict__ out) {
  int t = blockIdx.x * blockDim.x + threadIdx.x;
  int total = NB * NC * HW0;
  if (t >= total) return;
  int p = t % HW0;
  int c = (t / HW0) % NC;
  int b = t / (HW0 * NC);
  int i = p / W0, j = p % W0;
  float sum = 0.f;
#pragma unroll
  for (int kh = 0; kh < 3; ++kh) {
    int pi = i - kh + 1;
    if (pi < 0 || pi >= H0) continue;
#pragma unroll
    for (int kw = 0; kw < 3; ++kw) {
      int pj = j - kw + 1;
      if (pj < 0 || pj >= W0) continue;
      sum += G[((size_t)b * HW0 + pi * W0 + pj) * CD + c * 9 + kh * 3 + kw];
    }
  }
  out[t] = sum + x[t];
}

static inline size_t rup(size_t x) { return (x + 255) & ~(size_t)255; }

extern "C" void kernel_launch(void* const* d_in, const int* in_sizes, int n_in,
                              void* d_out, int out_size, void* d_ws, size_t ws_size,
                              hipStream_t stream) {
  const float* x   = (const float*)d_in[0];
  const float* Wmb = (const float*)d_in[1];
  const float* bmb = (const float*)d_in[2];
  const float* amb = (const float*)d_in[3];
  const float* Wm  = (const float*)d_in[4];
  const float* bm  = (const float*)d_in[5];
  const float* am  = (const float*)d_in[6];
  const float* Wa  = (const float*)d_in[7];
  const float* ba  = (const float*)d_in[8];
  const float* aa  = (const float*)d_in[9];
  float* out = (float*)d_out;
  char* ws = (char*)d_ws;

  size_t off = 0;
  float* mb    = (float*)(ws + off); off = rup(off + sizeof(float) * NB * NCR * HW0);
  float* refs  = (float*)(ws + off); off = rup(off + sizeof(float) * NB * NC * LTOT);
  float* base  = (float*)(ws + off); off = rup(off + sizeof(float) * NB * NC * LTOT);
  float* m     = (float*)(ws + off); off = rup(off + sizeof(float) * NB * NCR * LTOT);
  _Float16* xq16 = (_Float16*)(ws + off); off = rup(off + sizeof(_Float16) * NB * HW0 * KP);
  _Float16* wn16 = (_Float16*)(ws + off); off = rup(off + sizeof(_Float16) * (size_t)NB * LP * KP);
  _Float16* bt16 = (_Float16*)(ws + off); off = rup(off + sizeof(_Float16) * (size_t)NB * CDP * LP);
  float* G     = (float*)(ws + off); off = rup(off + sizeof(float) * NB * HW0 * CD);

  // adaptive p-chunk: needs NB*pc*LP*(4+2) bytes
  int pc = HW0;
  {
    size_t avail = (ws_size > off) ? ws_size - off - 1024 : 0;
    while (pc > 128 && (size_t)NB * pc * LP * 6 > avail) {
      if (pc == HW0) pc = 1152;
      else if (pc == 1152) pc = 768;
      else if (pc == 768) pc = 384;
      else pc = 128;
    }
  }
  float* scbuf = (float*)(ws + off); off = rup(off + sizeof(float) * (size_t)NB * pc * LP);
  _Float16* attn16 = (_Float16*)(ws + off);

  const int th = 256;
  k_conv1x1<<<(NB * NCR * HW0 + th - 1) / th, th, 0, stream>>>(x, Wmb, bmb, amb, mb, NC, NCR, HW0);
  k_build_refs<<<(NB * NC * LTOT + th - 1) / th, th, 0, stream>>>(x, refs);
  k_conv1x1<<<(NB * NC * LTOT + th - 1) / th, th, 0, stream>>>(refs, Wa, ba, aa, base, NC, NC, LTOT);
  k_conv1x1<<<(NB * NCR * LTOT + th - 1) / th, th, 0, stream>>>(refs, Wm, bm, am, m, NC, NCR, LTOT);
  k_build_xq<<<NB * HW0, 256, 0, stream>>>(mb, xq16);
  k_build_wn<<<NB * LP, 256, 0, stream>>>(m, wn16);
  k_build_brawT<<<(NB * CDP * LP + th - 1) / th, th, 0, stream>>>(base, bt16);

  for (int p0 = 0; p0 < HW0; p0 += pc) {
    // scores[b, p(pc), l(LP)] = xq . wn
    dim3 g1(LP / 128, pc / 128, NB);
    k_gemm_nt_f16<<<g1, 256, 0, stream>>>(
        xq16 + (size_t)p0 * KP, wn16, scbuf,
        KP, KP, KP, LP, LP,
        (long long)HW0 * KP, (long long)LP * KP, (long long)pc * LP);
    k_softmax<<<NB * pc, 256, 0, stream>>>(scbuf, attn16);
    // G[b, p, cd] = attn . BrawT
    dim3 g2(CDP / 128, pc / 128, NB);
    k_gemm_nt_f16<<<g2, 256, 0, stream>>>(
        attn16, bt16, G + (size_t)p0 * CD,
        LP, LP, LP, CD, CD,
        (long long)pc * LP, (long long)CDP * LP, (long long)HW0 * CD);
  }
  k_final<<<(NB * NC * HW0 + th - 1) / th, th, 0, stream>>>(G, x, out);
}

// Round 6
// 365.500 us; speedup vs baseline: 5.6941x; 1.2410x over previous
//
#include <hip/hip_runtime.h>
#include <math.h>

#define NB 2
#define NC 50
#define NCR 25
#define H0 48
#define W0 48
#define HW0 2304
#define LTOT 7470
#define LP 7552      // LTOT padded to 128
#define K225 225
#define KP 256       // 225 padded to 256
#define CD 450       // C*9
#define CDP 512      // padded to 128
#define NSPLIT 4
#define KC2 (LP / NSPLIT)   // 1888, multiple of 32

typedef _Float16 f16x8 __attribute__((ext_vector_type(8)));
typedef float f32x4 __attribute__((ext_vector_type(4)));

#define GLOAD_LDS16(gp, lp) __builtin_amdgcn_global_load_lds( \
    (const __attribute__((address_space(1))) void*)(gp),      \
    (__attribute__((address_space(3))) void*)(lp), 16, 0, 0)

__device__ __forceinline__ void decode_pix(int pix, int& s, int& off, int& d) {
  if (pix < 2304)      { s = 0; off = 0;    d = 48; }
  else if (pix < 4153) { s = 1; off = 2304; d = 43; }
  else if (pix < 5597) { s = 2; off = 4153; d = 38; }
  else if (pix < 6686) { s = 3; off = 5597; d = 33; }
  else                 { s = 4; off = 6686; d = 28; }
}

__device__ __forceinline__ float cubw(float t) {
  const float a = -0.75f;
  float at = fabsf(t);
  float w1 = ((a + 2.f) * at - (a + 3.f)) * at * at + 1.f;
  float w2 = (((at - 5.f) * at + 8.f) * at - 4.f) * a;
  return at <= 1.f ? w1 : (at < 2.f ? w2 : 0.f);
}

__global__ void k_conv1x1(const float* __restrict__ in, const float* __restrict__ Wt,
                          const float* __restrict__ bias, const float* __restrict__ slope,
                          float* __restrict__ out, int Cin, int O, int P) {
  int t = blockIdx.x * blockDim.x + threadIdx.x;
  int total = NB * O * P;
  if (t >= total) return;
  int pix = t % P;
  int o = (t / P) % O;
  int b = t / (P * O);
  float acc = bias[o];
  const float* ip = in + (size_t)b * Cin * P + pix;
  const float* wr = Wt + o * Cin;
  for (int c = 0; c < Cin; ++c) acc = fmaf(wr[c], ip[(size_t)c * P], acc);
  float a = slope[0];
  out[t] = acc >= 0.f ? acc : a * acc;
}

__global__ void k_build_refs(const float* __restrict__ x, float* __restrict__ refs) {
  int t = blockIdx.x * blockDim.x + threadIdx.x;
  int total = NB * NC * LTOT;
  if (t >= total) return;
  int pix = t % LTOT;
  int c = (t / LTOT) % NC;
  int b = t / (LTOT * NC);
  int s, off, d;
  decode_pix(pix, s, off, d);
  float v;
  const float* xb = x + ((size_t)b * NC + c) * HW0;
  if (s == 0) {
    v = xb[pix];
  } else {
    int rem = pix - off;
    int oy = rem / d, ox = rem % d;
    float scale = 47.f / (float)(d - 1);
    float sy = oy * scale, sx = ox * scale;
    float fy0 = floorf(sy), fx0 = floorf(sx);
    int iy = (int)fy0, ix = (int)fx0;
    float fy = sy - fy0, fx = sx - fx0;
    float wy[4], wx[4];
#pragma unroll
    for (int dd = 0; dd < 4; ++dd) {
      wy[dd] = cubw(fy - (float)(dd - 1));
      wx[dd] = cubw(fx - (float)(dd - 1));
    }
    float acc = 0.f;
#pragma unroll
    for (int p = 0; p < 4; ++p) {
      int yy = min(max(iy + p - 1, 0), 47);
      float rowacc = 0.f;
#pragma unroll
      for (int q = 0; q < 4; ++q) {
        int xx = min(max(ix + q - 1, 0), 47);
        rowacc = fmaf(wx[q], xb[yy * 48 + xx], rowacc);
      }
      acc = fmaf(wy[p], rowacc, acc);
    }
    v = acc;
  }
  refs[t] = v;
}

__global__ void k_build_xq(const float* __restrict__ mb, _Float16* __restrict__ xq) {
  int bp = blockIdx.x;
  int b = bp / HW0, p = bp % HW0;
  int i = p / W0, j = p % W0;
  int k = threadIdx.x;
  float v = 0.f;
  if (k < K225) {
    int c = k / 9, r = k % 9, di = r / 3, dj = r % 3;
    int yy = i + di - 1, xx = j + dj - 1;
    if (yy >= 0 && yy < H0 && xx >= 0 && xx < W0)
      v = mb[((size_t)b * NCR + c) * HW0 + yy * W0 + xx];
  }
  xq[(size_t)bp * KP + k] = (_Float16)v;
}

__global__ void k_build_wn(const float* __restrict__ m, _Float16* __restrict__ wn) {
  __shared__ float red[256];
  int bl = blockIdx.x;
  int b = bl / LP, l = bl % LP;
  int k = threadIdx.x;
  if (l >= LTOT) {
    wn[(size_t)bl * KP + k] = (_Float16)0.f;
    return;
  }
  int s, off, d;
  decode_pix(l, s, off, d);
  int rem = l - off;
  int y = rem / d, x = rem % d;
  float v = 0.f;
  if (k < K225) {
    int c = k / 9, r = k % 9, di = r / 3, dj = r % 3;
    int yy = y + di - 1, xx = x + dj - 1;
    if (yy >= 0 && yy < d && xx >= 0 && xx < d)
      v = m[((size_t)b * NCR + c) * LTOT + off + yy * d + xx];
  }
  red[k] = v * v;
  __syncthreads();
  for (int st = 128; st > 0; st >>= 1) {
    if (k < st) red[k] += red[k + st];
    __syncthreads();
  }
  float norm = sqrtf(red[0]);
  float sc = 10.f / fmaxf(norm, 1e-4f);
  wn[(size_t)bl * KP + k] = (_Float16)(v * sc);
}

__global__ void k_build_brawT(const float* __restrict__ base, _Float16* __restrict__ BT) {
  int t = blockIdx.x * blockDim.x + threadIdx.x;
  int total = NB * CDP * LP;
  if (t >= total) return;
  int l = t % LP;
  int cd = (t / LP) % CDP;
  int b = t / (LP * CDP);
  float v = 0.f;
  if (cd < CD && l < LTOT) {
    int s, off, d;
    decode_pix(l, s, off, d);
    int rem = l - off;
    int y = rem / d, x = rem % d;
    int c = cd / 9, r = cd % 9, di = r / 3, dj = r % 3;
    int yy = y + di - 1, xx = x + dj - 1;
    if (yy >= 0 && yy < d && xx >= 0 && xx < d)
      v = 0.25f * base[((size_t)b * NC + c) * LTOT + off + yy * d + xx];
  }
  BT[t] = (_Float16)v;
}

// C[m,n] = sum_{k<KC} A[m, s*KC+k]*B[n, s*KC+k], blockIdx.z = b*nsplit + s.
// Writes the full 128x128 tile (buffers padded).
__global__ __launch_bounds__(256) void k_gemm_nt_f16(
    const _Float16* __restrict__ A, const _Float16* __restrict__ Bm,
    float* __restrict__ Cm, int KC, int lda, int ldb, int ldc, int nsplit,
    long long sA, long long sB, long long sC) {
  __shared__ _Float16 As[128 * 32];
  __shared__ _Float16 Bs[128 * 32];
  int z = blockIdx.z;
  int b = z / nsplit, s = z % nsplit;
  const _Float16* Ab = A + b * sA + (size_t)s * KC;
  const _Float16* Bb = Bm + b * sB + (size_t)s * KC;
  float* Cb = Cm + z * sC;
  int m0 = blockIdx.y * 128, n0 = blockIdx.x * 128;
  int t = threadIdx.x;
  int lane = t & 63, wid = t >> 6;
  int wr = wid >> 1, wc = wid & 1;
  f32x4 acc[4][4] = {};
  for (int k0 = 0; k0 < KC; k0 += 32) {
#pragma unroll
    for (int i = 0; i < 2; ++i) {
      int e = i * 256 + t;
      int r = e >> 2, c = e & 3;
      GLOAD_LDS16(Ab + (size_t)(m0 + r) * lda + k0 + c * 8, As + (size_t)e * 8);
      GLOAD_LDS16(Bb + (size_t)(n0 + r) * ldb + k0 + c * 8, Bs + (size_t)e * 8);
    }
    __syncthreads();
    int rla = (wr * 64 + (lane & 15)) * 32 + (lane >> 4) * 8;
    int rlb = (wc * 64 + (lane & 15)) * 32 + (lane >> 4) * 8;
    f16x8 af[4], bf[4];
#pragma unroll
    for (int mi = 0; mi < 4; ++mi) af[mi] = *(const f16x8*)&As[rla + mi * 16 * 32];
#pragma unroll
    for (int ni = 0; ni < 4; ++ni) bf[ni] = *(const f16x8*)&Bs[rlb + ni * 16 * 32];
#pragma unroll
    for (int mi = 0; mi < 4; ++mi)
#pragma unroll
      for (int ni = 0; ni < 4; ++ni)
        acc[mi][ni] = __builtin_amdgcn_mfma_f32_16x16x32_f16(af[mi], bf[ni], acc[mi][ni], 0, 0, 0);
    __syncthreads();
  }
  int col0 = lane & 15;
  int row0 = (lane >> 4) * 4;
#pragma unroll
  for (int mi = 0; mi < 4; ++mi) {
#pragma unroll
    for (int ni = 0; ni < 4; ++ni) {
      int n = n0 + wc * 64 + ni * 16 + col0;
#pragma unroll
      for (int r = 0; r < 4; ++r) {
        int mrow = m0 + wr * 64 + mi * 16 + row0 + r;
        Cb[(size_t)mrow * ldc + n] = acc[mi][ni][r];
      }
    }
  }
}

// in-place: row of LP fp32 scores -> softmax -> fp16 attn written into the
// FIRST HALF of the same row's storage (reads staged through LDS first).
__global__ void k_softmax(float* __restrict__ S) {
  __shared__ float buf[LTOT];
  __shared__ float red[256];
  size_t row = blockIdx.x;
  float* r = S + row * LP;
  _Float16* w = (_Float16*)r;
  int tid = threadIdx.x;
  float mx = -1e30f;
  for (int i = tid; i < LTOT; i += 256) {
    float v = r[i];
    buf[i] = v;
    mx = fmaxf(mx, v);
  }
  red[tid] = mx;
  __syncthreads();
  for (int st = 128; st > 0; st >>= 1) {
    if (tid < st) red[tid] = fmaxf(red[tid], red[tid + st]);
    __syncthreads();
  }
  mx = red[0];
  __syncthreads();
  float sm = 0.f;
  for (int i = tid; i < LTOT; i += 256) {
    float e = __expf(buf[i] - mx);
    buf[i] = e;
    sm += e;
  }
  red[tid] = sm;
  __syncthreads();
  for (int st = 128; st > 0; st >>= 1) {
    if (tid < st) red[tid] += red[tid + st];
    __syncthreads();
  }
  float inv = 1.f / red[0];
  __syncthreads();
  for (int i = tid; i < LTOT; i += 256) w[i] = (_Float16)(buf[i] * inv);
  for (int i = LTOT + tid; i < LP; i += 256) w[i] = (_Float16)0.f;
}

// G[b, p0+p, cd<450] = sum_s Gp[(b*NSPLIT+s), p, cd(512-stride)]
__global__ void k_reduceG(const float* __restrict__ Gp, float* __restrict__ G,
                          int pc, int p0) {
  int t = blockIdx.x * blockDim.x + threadIdx.x;
  int total = NB * pc * CD;
  if (t >= total) return;
  int cd = t % CD;
  int p = (t / CD) % pc;
  int b = t / (CD * pc);
  float acc = 0.f;
#pragma unroll
  for (int s = 0; s < NSPLIT; ++s)
    acc += Gp[(((size_t)(b * NSPLIT + s) * pc) + p) * CDP + cd];
  G[((size_t)b * HW0 + p0 + p) * CD + cd] = acc;
}

__global__ void k_final(const float* __restrict__ G, const float* __restrict__ x,
                        float* __restrict__ out) {
  int t = blockIdx.x * blockDim.x + threadIdx.x;
  int total = NB * NC * HW0;
  if (t >= total) return;
  int p = t % HW0;
  int c = (t / HW0) % NC;
  int b = t / (HW0 * NC);
  int i = p / W0, j = p % W0;
  float sum = 0.f;
#pragma unroll
  for (int kh = 0; kh < 3; ++kh) {
    int pi = i - kh + 1;
    if (pi < 0 || pi >= H0) continue;
#pragma unroll
    for (int kw = 0; kw < 3; ++kw) {
      int pj = j - kw + 1;
      if (pj < 0 || pj >= W0) continue;
      sum += G[((size_t)b * HW0 + pi * W0 + pj) * CD + c * 9 + kh * 3 + kw];
    }
  }
  out[t] = sum + x[t];
}

static inline size_t rup(size_t x) { return (x + 255) & ~(size_t)255; }

extern "C" void kernel_launch(void* const* d_in, const int* in_sizes, int n_in,
                              void* d_out, int out_size, void* d_ws, size_t ws_size,
                              hipStream_t stream) {
  const float* x   = (const float*)d_in[0];
  const float* Wmb = (const float*)d_in[1];
  const float* bmb = (const float*)d_in[2];
  const float* amb = (const float*)d_in[3];
  const float* Wm  = (const float*)d_in[4];
  const float* bm  = (const float*)d_in[5];
  const float* am  = (const float*)d_in[6];
  const float* Wa  = (const float*)d_in[7];
  const float* ba  = (const float*)d_in[8];
  const float* aa  = (const float*)d_in[9];
  float* out = (float*)d_out;
  char* ws = (char*)d_ws;

  size_t off = 0;
  float* mb    = (float*)(ws + off); off = rup(off + sizeof(float) * NB * NCR * HW0);
  float* refs  = (float*)(ws + off); off = rup(off + sizeof(float) * NB * NC * LTOT);
  float* base  = (float*)(ws + off); off = rup(off + sizeof(float) * NB * NC * LTOT);
  float* m     = (float*)(ws + off); off = rup(off + sizeof(float) * NB * NCR * LTOT);
  _Float16* xq16 = (_Float16*)(ws + off); off = rup(off + sizeof(_Float16) * NB * HW0 * KP);
  _Float16* wn16 = (_Float16*)(ws + off); off = rup(off + sizeof(_Float16) * (size_t)NB * LP * KP);
  _Float16* bt16 = (_Float16*)(ws + off); off = rup(off + sizeof(_Float16) * (size_t)NB * CDP * LP);
  float* G     = (float*)(ws + off); off = rup(off + sizeof(float) * NB * HW0 * CD);

  // per-chunk: scores [NB][pc][LP] fp32 (attn fp16 aliased in-place)
  //          + Gp [NB*NSPLIT][pc][CDP] fp32
  int pc = HW0;
  {
    size_t avail = (ws_size > off) ? ws_size - off - 1024 : 0;
    size_t per = (size_t)NB * (LP * 4 + NSPLIT * CDP * 4);
    while (pc > 128 && (size_t)pc * per > avail) {
      if (pc == HW0) pc = 1152;
      else if (pc == 1152) pc = 768;
      else if (pc == 768) pc = 384;
      else pc = 128;
    }
  }
  float* scbuf = (float*)(ws + off); off = rup(off + sizeof(float) * (size_t)NB * pc * LP);
  float* Gp    = (float*)(ws + off);

  const int th = 256;
  k_conv1x1<<<(NB * NCR * HW0 + th - 1) / th, th, 0, stream>>>(x, Wmb, bmb, amb, mb, NC, NCR, HW0);
  k_build_refs<<<(NB * NC * LTOT + th - 1) / th, th, 0, stream>>>(x, refs);
  k_conv1x1<<<(NB * NC * LTOT + th - 1) / th, th, 0, stream>>>(refs, Wa, ba, aa, base, NC, NC, LTOT);
  k_conv1x1<<<(NB * NCR * LTOT + th - 1) / th, th, 0, stream>>>(refs, Wm, bm, am, m, NC, NCR, LTOT);
  k_build_xq<<<NB * HW0, 256, 0, stream>>>(mb, xq16);
  k_build_wn<<<NB * LP, 256, 0, stream>>>(m, wn16);
  k_build_brawT<<<(NB * CDP * LP + th - 1) / th, th, 0, stream>>>(base, bt16);

  for (int p0 = 0; p0 < HW0; p0 += pc) {
    // scores[b, p, l] = xq . wn   (fp32, full LP cols incl. zero pad)
    dim3 g1(LP / 128, pc / 128, NB);
    k_gemm_nt_f16<<<g1, 256, 0, stream>>>(
        xq16 + (size_t)p0 * KP, wn16, scbuf,
        KP, KP, KP, LP, 1,
        (long long)HW0 * KP, (long long)LP * KP, (long long)pc * LP);
    // softmax in place; attn fp16 lives in first half of each score row
    k_softmax<<<NB * pc, 256, 0, stream>>>(scbuf);
    // Gp[(b,s), p, cd] = attn(k-chunk s) . BrawT(k-chunk s)
    dim3 g2(CDP / 128, pc / 128, NB * NSPLIT);
    k_gemm_nt_f16<<<g2, 256, 0, stream>>>(
        (const _Float16*)scbuf, bt16, Gp,
        KC2, 2 * LP, LP, CDP, NSPLIT,
        (long long)pc * 2 * LP, (long long)CDP * LP, (long long)pc * CDP);
    k_reduceG<<<(NB * pc * CD + th - 1) / th, th, 0, stream>>>(Gp, G, pc, p0);
  }
  k_final<<<(NB * NC * HW0 + th - 1) / th, th, 0, stream>>>(G, x, out);
}